// Round 8
// baseline (64894.855 us; speedup 1.0000x reference)
//
#include <hip/hip_runtime.h>
#include <hip/hip_bf16.h>

#define BB 256
#define TT 1024
#define DIN 64
#define HH 1024
#define NL 3
#define ALPHA 0.5f
#define RING 4
#define NWG 192

typedef __attribute__((ext_vector_type(8))) short bf16x8;
typedef __attribute__((ext_vector_type(4))) float f32x4;

// ---- workspace byte offsets ----
static const size_t WB_OFF  = 0;          // bf16 weights            10,616,832 B
static const size_t S16_OFF = 10617344;   // bf16 [RING][L][B][H]     6,291,456 B
static const size_t S32_OFF = 16908800;   // f32  [L][B][H]           3,145,728 B
static const size_t CNT_OFF = 20054528;   // u32  [L][2][1032]           24,768 B

#define WIN0_E   0
#define WIN12_E  65536
#define WRES_E   2162688

#define CIDX(l, bi) (((l) * 2 + (bi)) * 1032)

// ---------------- weight fp32 -> bf16 convert ----------------
__global__ void convert_kernel(const float* __restrict__ w_in0,
                               const float* __restrict__ w_in_rest,
                               const float* __restrict__ w_res,
                               __hip_bfloat16* __restrict__ Wb)
{
    const size_t total = 65536ull + 2097152ull + 3145728ull;
    for (size_t i = (size_t)blockIdx.x * blockDim.x + threadIdx.x; i < total;
         i += (size_t)gridDim.x * blockDim.x) {
        float v;
        if (i < 65536)            v = w_in0[i];
        else if (i < 2162688)     v = w_in_rest[i - 65536];
        else                      v = w_res[i - 2162688];
        Wb[i] = __float2bfloat16(v);
    }
}

__device__ __forceinline__ float tanh_fast(float x) {
    float e = __expf(2.0f * x);
    return 1.0f - 2.0f / (e + 1.0f);
}

// 16B state load from the LLC (bypass L1/L2): 4 relaxed agent-scope dword loads.
__device__ __forceinline__ bf16x8 llc_load16(const unsigned short* p) {
    const unsigned int* q = (const unsigned int*)p;
    union { unsigned int u[4]; bf16x8 v; } x;
    x.u[0] = __hip_atomic_load(q + 0, __ATOMIC_RELAXED, __HIP_MEMORY_SCOPE_AGENT);
    x.u[1] = __hip_atomic_load(q + 1, __ATOMIC_RELAXED, __HIP_MEMORY_SCOPE_AGENT);
    x.u[2] = __hip_atomic_load(q + 2, __ATOMIC_RELAXED, __HIP_MEMORY_SCOPE_AGENT);
    x.u[3] = __hip_atomic_load(q + 3, __ATOMIC_RELAXED, __HIP_MEMORY_SCOPE_AGENT);
    return x.v;
}

// 8 consecutive f32 -> bf16x8 (for the l==0 x-operand)
__device__ __forceinline__ bf16x8 cvt_pack8(const float* p) {
    union { unsigned short s[8]; bf16x8 v; } x;
#pragma unroll
    for (int i = 0; i < 8; ++i) {
        __hip_bfloat16 h = __float2bfloat16(p[i]);
        x.s[i] = *(unsigned short*)&h;
    }
    return x.v;
}

// GEMM part with A streamed from LLC, B from LDS (conflict-free b128 layout).
template <int KTOT>
__device__ __forceinline__ void gemm_llc(const unsigned short* __restrict__ A0,
                                         const unsigned short* __restrict__ A1,
                                         const char* __restrict__ Bp,
                                         f32x4& a00, f32x4& a01, f32x4& a10, f32x4& a11)
{
#pragma unroll 4
    for (int k = 0; k < KTOT; k += 32) {
        bf16x8 a0 = llc_load16(A0 + k);
        bf16x8 a1 = llc_load16(A1 + k);
        bf16x8 b0 = *(const bf16x8*)(Bp + k * 64);
        bf16x8 b1 = *(const bf16x8*)(Bp + k * 64 + 256);
        a00 = __builtin_amdgcn_mfma_f32_16x16x32_bf16(a0, b0, a00, 0, 0, 0);
        a01 = __builtin_amdgcn_mfma_f32_16x16x32_bf16(a0, b1, a01, 0, 0, 0);
        a10 = __builtin_amdgcn_mfma_f32_16x16x32_bf16(a1, b0, a10, 0, 0, 0);
        a11 = __builtin_amdgcn_mfma_f32_16x16x32_bf16(a1, b1, a11, 0, 0, 0);
    }
}

// Persistent kernel, dataflow-synchronized: 192 wgs = 2 halves x 3 layers x 32 col-tiles.
// No grid barrier. State plane through LLC; per-(l,bi,t) publish counters.
__global__ __launch_bounds__(256, 1) void esn_main(
    const float* __restrict__ x,
    const unsigned short* __restrict__ Wb,
    unsigned short* __restrict__ S16,
    float* __restrict__ S32,
    unsigned int* __restrict__ cnt)
{
    __shared__ char Blds[131072];   // [W_in slice 64K][W_res slice 64K]

    const int wg  = blockIdx.x;           // 0..191
    const int bi  = wg / 96;
    const int rem = wg - bi * 96;
    const int l   = rem >> 5;
    const int ni  = rem & 31;
    const int n0  = ni * 32;

    const int tid  = threadIdx.x;
    const int lane = tid & 63;
    const int w    = tid >> 6;

    // ---- stage weight slice into LDS, once ----
    {
        const unsigned short* gWin = (l == 0) ? (Wb + WIN0_E)
                                              : (Wb + WIN12_E + (size_t)(l - 1) * HH * HH);
        const int kin  = (l == 0) ? DIN : HH;
        const int nblk = 32 * (kin >> 3);
        for (int idx = tid; idx < nblk; idx += 256) {
            int c   = idx & 31;
            int kb8 = idx >> 5;
            bf16x8 v = *(const bf16x8*)(gWin + (size_t)(n0 + c) * kin + kb8 * 8);
            *(bf16x8*)(Blds + (kb8 * 32 + c) * 16) = v;
        }
        const unsigned short* gWres = Wb + WRES_E + (size_t)l * HH * HH;
        for (int idx = tid; idx < 32 * 128; idx += 256) {
            int c   = idx & 31;
            int kb8 = idx >> 5;
            bf16x8 v = *(const bf16x8*)(gWres + (size_t)(n0 + c) * HH + kb8 * 8);
            *(bf16x8*)(Blds + 65536 + (kb8 * 32 + c) * 16) = v;
        }
    }
    __syncthreads();

    const int ar = lane & 15;
    const int kq = (lane >> 4) << 3;
    const int m0 = bi * 128 + w * 32;
    const char* BpIn  = Blds + ((kq >> 3) * 32 + ar) * 16;
    const char* BpRes = BpIn + 65536;
    const int rb = (lane >> 4) << 2;
    const int cc = lane & 15;

    const size_t PLANE = (size_t)BB * HH;

    // fp32 state master in registers for the whole T loop
    float mst[2][2][4];
#pragma unroll
    for (int i = 0; i < 2; ++i)
#pragma unroll
        for (int j = 0; j < 2; ++j)
#pragma unroll
            for (int r = 0; r < 4; ++r) mst[i][j][r] = 0.f;

    for (int t = 0; t < TT; ++t) {
        // ---- dependency gates (leader spins, others wait at barrier) ----
        if (tid == 0) {
            const bool gown = (t >= 1);
            const bool glow = (l > 0);
            const bool gup  = (l < NL - 1) && (t >= RING);
            const unsigned int* pown = cnt + (gown ? CIDX(l, bi) + (t - 1) : 0);
            const unsigned int* plow = cnt + (glow ? CIDX(l - 1, bi) + t : 0);
            const unsigned int* pup  = cnt + (gup  ? CIDX(l + 1, bi) + (t - RING) : 0);
            while (true) {
                bool ok = true;
                if (gown) ok &= (__hip_atomic_load(pown, __ATOMIC_RELAXED,
                                                   __HIP_MEMORY_SCOPE_AGENT) >= 32u);
                if (glow) ok &= (__hip_atomic_load(plow, __ATOMIC_RELAXED,
                                                   __HIP_MEMORY_SCOPE_AGENT) >= 32u);
                if (gup)  ok &= (__hip_atomic_load(pup, __ATOMIC_RELAXED,
                                                   __HIP_MEMORY_SCOPE_AGENT) >= 32u);
                if (ok) break;
                __builtin_amdgcn_s_sleep(1);
            }
        }
        __syncthreads();

        f32x4 a00 = {0.f, 0.f, 0.f, 0.f};
        f32x4 a01 = a00, a10 = a00, a11 = a00;

        // part 1: h_l(t-1) @ W_res^T  (skip at t==0: state is zero)
        if (t >= 1) {
            const unsigned short* base = S16 + ((size_t)((t - 1) & 3) * NL + l) * PLANE;
            const unsigned short* A0 = base + (size_t)(m0 + ar) * HH + kq;
            gemm_llc<HH>(A0, A0 + 16 * HH, BpRes, a00, a01, a10, a11);
        }
        // part 0: input @ W_in^T
        if (l == 0) {
            const float* xr0 = x + ((size_t)(m0 + ar) * TT + t) * DIN + kq;
            const float* xr1 = x + ((size_t)(m0 + 16 + ar) * TT + t) * DIN + kq;
#pragma unroll
            for (int k = 0; k < DIN; k += 32) {
                bf16x8 a0 = cvt_pack8(xr0 + k);
                bf16x8 a1 = cvt_pack8(xr1 + k);
                bf16x8 b0 = *(const bf16x8*)(BpIn + k * 64);
                bf16x8 b1 = *(const bf16x8*)(BpIn + k * 64 + 256);
                a00 = __builtin_amdgcn_mfma_f32_16x16x32_bf16(a0, b0, a00, 0, 0, 0);
                a01 = __builtin_amdgcn_mfma_f32_16x16x32_bf16(a0, b1, a01, 0, 0, 0);
                a10 = __builtin_amdgcn_mfma_f32_16x16x32_bf16(a1, b0, a10, 0, 0, 0);
                a11 = __builtin_amdgcn_mfma_f32_16x16x32_bf16(a1, b1, a11, 0, 0, 0);
            }
        } else {
            const unsigned short* base = S16 + ((size_t)(t & 3) * NL + (l - 1)) * PLANE;
            const unsigned short* A0 = base + (size_t)(m0 + ar) * HH + kq;
            gemm_llc<HH>(A0, A0 + 16 * HH, BpIn, a00, a01, a10, a11);
        }

        // ---- epilogue: leaky update (reg master), publish bf16 via LLC stores ----
        unsigned short* Sn = S16 + ((size_t)(t & 3) * NL + l) * PLANE;
#pragma unroll
        for (int i = 0; i < 2; ++i)
#pragma unroll
        for (int j = 0; j < 2; ++j) {
            f32x4 acc = (i == 0) ? ((j == 0) ? a00 : a01) : ((j == 0) ? a10 : a11);
#pragma unroll
            for (int r = 0; r < 4; ++r) {
                float hnew = (1.0f - ALPHA) * mst[i][j][r] + ALPHA * tanh_fast(acc[r]);
                mst[i][j][r] = hnew;
                int b = m0 + i * 16 + rb + r;
                int h = n0 + j * 16 + cc;
                __hip_bfloat16 hb = __float2bfloat16(hnew);
                unsigned short hv = *(unsigned short*)&hb;
                unsigned short* sp = Sn + (size_t)b * HH + h;
                asm volatile("global_store_short %0, %1, off sc0 sc1"
                             :: "v"(sp), "v"(hv) : "memory");
            }
        }
        // all threads drain their stores, then leader publishes the counter
        asm volatile("s_waitcnt vmcnt(0)" ::: "memory");
        __syncthreads();
        if (tid == 0) {
            __hip_atomic_fetch_add(cnt + CIDX(l, bi) + t, 1u,
                                   __ATOMIC_RELAXED, __HIP_MEMORY_SCOPE_AGENT);
        }
        asm volatile("" ::: "memory");
    }

    // final fp32 state dump for the readout
#pragma unroll
    for (int i = 0; i < 2; ++i)
#pragma unroll
    for (int j = 0; j < 2; ++j)
#pragma unroll
    for (int r = 0; r < 4; ++r) {
        int b = m0 + i * 16 + rb + r;
        int h = n0 + j * 16 + cc;
        S32[((size_t)l * BB + b) * HH + h] = mst[i][j][r];
    }
}

// ---------------- readout ----------------
__global__ void out_kernel(const float* __restrict__ S32,
                           const float* __restrict__ w_out,
                           const float* __restrict__ b_out,
                           float* __restrict__ out)
{
    int b = blockIdx.x;
    int tid = threadIdx.x;
    float p = 0.f;
    for (int idx = tid; idx < NL * HH; idx += 256) {
        int l = idx >> 10;
        int h = idx & (HH - 1);
        p += S32[((size_t)l * BB + b) * HH + h] * w_out[idx];
    }
    __shared__ float red[256];
    red[tid] = p;
    __syncthreads();
    for (int off = 128; off > 0; off >>= 1) {
        if (tid < off) red[tid] += red[tid + off];
        __syncthreads();
    }
    if (tid == 0) out[b] = red[0] + b_out[0];
}

extern "C" void kernel_launch(void* const* d_in, const int* in_sizes, int n_in,
                              void* d_out, int out_size, void* d_ws, size_t ws_size,
                              hipStream_t stream)
{
    const float* x         = (const float*)d_in[0];
    const float* W_in0     = (const float*)d_in[1];
    const float* W_in_rest = (const float*)d_in[2];
    const float* W_res     = (const float*)d_in[3];
    const float* w_out     = (const float*)d_in[4];
    const float* b_out     = (const float*)d_in[5];

    char* ws = (char*)d_ws;
    __hip_bfloat16*       Wbh  = (__hip_bfloat16*)(ws + WB_OFF);
    const unsigned short* Wbp  = (const unsigned short*)(ws + WB_OFF);
    unsigned short*       S16p = (unsigned short*)(ws + S16_OFF);
    float*                S32p = (float*)(ws + S32_OFF);
    unsigned int*         cntp = (unsigned int*)(ws + CNT_OFF);

    convert_kernel<<<4096, 256, 0, stream>>>(W_in0, W_in_rest, W_res, Wbh);
    hipMemsetAsync(ws + CNT_OFF, 0, 24768, stream);   // zero publish counters

    void* args[] = { (void*)&x, (void*)&Wbp, (void*)&S16p, (void*)&S32p, (void*)&cntp };
    hipLaunchCooperativeKernel((const void*)esn_main, dim3(NWG), dim3(256),
                               args, 0, stream);

    out_kernel<<<BB, 256, 0, stream>>>(S32p, w_out, b_out, (float*)d_out);
}

// Round 12
// 22884.909 us; speedup vs baseline: 2.8357x; 2.8357x over previous
//
#include <hip/hip_runtime.h>
#include <hip/hip_bf16.h>

#define BB 256
#define TT 1024
#define DIN 64
#define HH 1024
#define NL 3
#define ALPHA 0.5f
#define SBUF (NL * BB * HH)
#define NWG 192

typedef __attribute__((ext_vector_type(8))) short bf16x8;
typedef __attribute__((ext_vector_type(4))) float f32x4;

// ---- workspace byte offsets ----
static const size_t WB_OFF  = 0;          // bf16 weights       10,616,832 B
static const size_t S16_OFF = 10617344;   // bf16 [2][L][B][H]   3,145,728 B
static const size_t S32_OFF = 13763072;   // f32  [L][B][H]      3,145,728 B
static const size_t BAR_OFF = 16908800;   // barrier block             256 B

#define WIN0_E   0
#define WIN12_E  65536
#define WRES_E   2162688

// ---------------- weight fp32 -> bf16 convert ----------------
__global__ void convert_kernel(const float* __restrict__ w_in0,
                               const float* __restrict__ w_in_rest,
                               const float* __restrict__ w_res,
                               __hip_bfloat16* __restrict__ Wb)
{
    const size_t total = 65536ull + 2097152ull + 3145728ull;
    for (size_t i = (size_t)blockIdx.x * blockDim.x + threadIdx.x; i < total;
         i += (size_t)gridDim.x * blockDim.x) {
        float v;
        if (i < 65536)            v = w_in0[i];
        else if (i < 2162688)     v = w_in_rest[i - 65536];
        else                      v = w_res[i - 2162688];
        Wb[i] = __float2bfloat16(v);
    }
}

__device__ __forceinline__ float tanh_fast(float x) {
    float e = __expf(2.0f * x);       // inf-safe
    return 1.0f - 2.0f / (e + 1.0f);
}

// 8 consecutive f32 -> bf16x8 (l==0 x-operand)
__device__ __forceinline__ bf16x8 cvt_pack8(const float* p) {
    union { unsigned short s[8]; bf16x8 v; } x;
#pragma unroll
    for (int i = 0; i < 8; ++i) {
        __hip_bfloat16 h = __float2bfloat16(p[i]);
        x.s[i] = *(unsigned short*)&h;
    }
    return x.v;
}

// Lean grid barrier (unchanged from v5 — measured working at 27.9ms).
__device__ __forceinline__ void grid_barrier(unsigned int* __restrict__ bar, int step)
{
    __syncthreads();
    if (threadIdx.x == 0) {
        const unsigned int want = (unsigned int)(step + 1);
        unsigned int old = __hip_atomic_fetch_add(bar, 1u, __ATOMIC_RELEASE,
                                                  __HIP_MEMORY_SCOPE_AGENT);
        if (old == (unsigned int)NWG * want - 1u) {
            __hip_atomic_store(bar + 32, want, __ATOMIC_RELEASE,
                               __HIP_MEMORY_SCOPE_AGENT);
        } else {
            while (__hip_atomic_load(bar + 32, __ATOMIC_RELAXED,
                                     __HIP_MEMORY_SCOPE_AGENT) < want)
                __builtin_amdgcn_s_sleep(2);
        }
        __builtin_amdgcn_fence(__ATOMIC_ACQUIRE, "agent");
    }
    __syncthreads();
}

// Fused dual GEMM (res + in, both K=1024, same accumulator), register
// double-buffered A prefetch: 4-iter chunks, 8 loads in flight, all
// indices compile-time (full unroll).
__device__ __forceinline__ void gemm_dual(const unsigned short* __restrict__ Ar,
                                          const unsigned short* __restrict__ Ai,
                                          const char* __restrict__ Bpr,
                                          const char* __restrict__ Bpi,
                                          f32x4& a00, f32x4& a01)
{
    bf16x8 br[2][4], bn[2][4];
#pragma unroll
    for (int c = 0; c < 4; ++c) {
        br[0][c] = *(const bf16x8*)(Ar + c * 32);
        bn[0][c] = *(const bf16x8*)(Ai + c * 32);
    }
#pragma unroll
    for (int ch = 0; ch < 8; ++ch) {
        const int cur = ch & 1;
        if (ch < 7) {
#pragma unroll
            for (int c = 0; c < 4; ++c) {
                br[cur ^ 1][c] = *(const bf16x8*)(Ar + ((ch + 1) * 4 + c) * 32);
                bn[cur ^ 1][c] = *(const bf16x8*)(Ai + ((ch + 1) * 4 + c) * 32);
            }
        }
#pragma unroll
        for (int c = 0; c < 4; ++c) {
            const int k = (ch * 4 + c) * 32;
            bf16x8 b0 = *(const bf16x8*)(Bpr + k * 64);
            bf16x8 b1 = *(const bf16x8*)(Bpr + k * 64 + 256);
            a00 = __builtin_amdgcn_mfma_f32_16x16x32_bf16(br[cur][c], b0, a00, 0, 0, 0);
            a01 = __builtin_amdgcn_mfma_f32_16x16x32_bf16(br[cur][c], b1, a01, 0, 0, 0);
            bf16x8 c0 = *(const bf16x8*)(Bpi + k * 64);
            bf16x8 c1 = *(const bf16x8*)(Bpi + k * 64 + 256);
            a00 = __builtin_amdgcn_mfma_f32_16x16x32_bf16(bn[cur][c], c0, a00, 0, 0, 0);
            a01 = __builtin_amdgcn_mfma_f32_16x16x32_bf16(bn[cur][c], c1, a01, 0, 0, 0);
        }
    }
}

// Single-stream chunked GEMM (res GEMM for l==0 wgs).
__device__ __forceinline__ void gemm_single(const unsigned short* __restrict__ Ar,
                                            const char* __restrict__ Bp,
                                            f32x4& a00, f32x4& a01)
{
    bf16x8 buf[2][4];
#pragma unroll
    for (int c = 0; c < 4; ++c) buf[0][c] = *(const bf16x8*)(Ar + c * 32);
#pragma unroll
    for (int ch = 0; ch < 8; ++ch) {
        const int cur = ch & 1;
        if (ch < 7) {
#pragma unroll
            for (int c = 0; c < 4; ++c)
                buf[cur ^ 1][c] = *(const bf16x8*)(Ar + ((ch + 1) * 4 + c) * 32);
        }
#pragma unroll
        for (int c = 0; c < 4; ++c) {
            const int k = (ch * 4 + c) * 32;
            bf16x8 b0 = *(const bf16x8*)(Bp + k * 64);
            bf16x8 b1 = *(const bf16x8*)(Bp + k * 64 + 256);
            a00 = __builtin_amdgcn_mfma_f32_16x16x32_bf16(buf[cur][c], b0, a00, 0, 0, 0);
            a01 = __builtin_amdgcn_mfma_f32_16x16x32_bf16(buf[cur][c], b1, a01, 0, 0, 0);
        }
    }
}

// Persistent kernel: 192 wgs x 512 threads = 2 halves x 3 layers x 32 col-tiles.
// 8 waves/wg (16 rows x 32 cols each) -> 2 waves/SIMD for latency hiding.
__global__ __launch_bounds__(512, 2) void esn_main(
    const float* __restrict__ x,
    const unsigned short* __restrict__ Wb,
    unsigned short* __restrict__ S16,
    float* __restrict__ S32,
    unsigned int* __restrict__ bar)
{
    __shared__ char Blds[131072];   // [W_in slice 64K][W_res slice 64K]

    const int wg  = blockIdx.x;           // 0..191
    const int bi  = wg / 96;
    const int rem = wg - bi * 96;
    const int l   = rem >> 5;
    const int ni  = rem & 31;
    const int n0  = ni * 32;

    const int tid  = threadIdx.x;
    const int lane = tid & 63;
    const int w    = tid >> 6;            // 0..7

    // ---- stage weight slice into LDS, once ----
    {
        const unsigned short* gWin = (l == 0) ? (Wb + WIN0_E)
                                              : (Wb + WIN12_E + (size_t)(l - 1) * HH * HH);
        const int kin  = (l == 0) ? DIN : HH;
        const int nblk = 32 * (kin >> 3);
        for (int idx = tid; idx < nblk; idx += 512) {
            int c   = idx & 31;
            int kb8 = idx >> 5;
            bf16x8 v = *(const bf16x8*)(gWin + (size_t)(n0 + c) * kin + kb8 * 8);
            *(bf16x8*)(Blds + (kb8 * 32 + c) * 16) = v;
        }
        const unsigned short* gWres = Wb + WRES_E + (size_t)l * HH * HH;
        for (int idx = tid; idx < 32 * 128; idx += 512) {
            int c   = idx & 31;
            int kb8 = idx >> 5;
            bf16x8 v = *(const bf16x8*)(gWres + (size_t)(n0 + c) * HH + kb8 * 8);
            *(bf16x8*)(Blds + 65536 + (kb8 * 32 + c) * 16) = v;
        }
    }
    __syncthreads();

    const int ar = lane & 15;
    const int kq = (lane >> 4) << 3;
    const int m0 = bi * 128 + w * 16;     // 16-row slice per wave
    const char* BpIn  = Blds + ((kq >> 3) * 32 + ar) * 16;
    const char* BpRes = BpIn + 65536;
    const int rb = (lane >> 4) << 2;
    const int cc = lane & 15;

    const size_t PLANE = (size_t)BB * HH;

    // fp32 state master in registers for the whole T loop: [j][r]
    float mst[2][4];
#pragma unroll
    for (int j = 0; j < 2; ++j)
#pragma unroll
        for (int r = 0; r < 4; ++r) mst[j][r] = 0.f;

    for (int s = 0; s < TT + NL - 1; ++s) {
        const int t = s - l;
        const unsigned short* Sc = S16 + (size_t)(s & 1) * SBUF;
        unsigned short*       Sn = S16 + (size_t)((s + 1) & 1) * SBUF;
        if (t >= 0 && t < TT) {
            f32x4 a00 = {0.f, 0.f, 0.f, 0.f};
            f32x4 a01 = a00;

            if (l == 0) {
                // res GEMM (K=1024) chunked
                const unsigned short* Ar = Sc + (size_t)(m0 + ar) * HH + kq;
                gemm_single(Ar, BpRes, a00, a01);
                // x GEMM (K=64)
                const float* xr = x + ((size_t)(m0 + ar) * TT + t) * DIN + kq;
#pragma unroll
                for (int k = 0; k < DIN; k += 32) {
                    bf16x8 a0 = cvt_pack8(xr + k);
                    bf16x8 b0 = *(const bf16x8*)(BpIn + k * 64);
                    bf16x8 b1 = *(const bf16x8*)(BpIn + k * 64 + 256);
                    a00 = __builtin_amdgcn_mfma_f32_16x16x32_bf16(a0, b0, a00, 0, 0, 0);
                    a01 = __builtin_amdgcn_mfma_f32_16x16x32_bf16(a0, b1, a01, 0, 0, 0);
                }
            } else {
                // fused res + in GEMMs (both K=1024, same accumulator)
                const unsigned short* Ar = Sc + (size_t)l * PLANE + (size_t)(m0 + ar) * HH + kq;
                const unsigned short* Ai = Sc + (size_t)(l - 1) * PLANE + (size_t)(m0 + ar) * HH + kq;
                gemm_dual(Ar, Ai, BpRes, BpIn, a00, a01);
            }

            // epilogue: leaky update (reg master), publish bf16
#pragma unroll
            for (int j = 0; j < 2; ++j) {
                f32x4 acc = (j == 0) ? a00 : a01;
#pragma unroll
                for (int r = 0; r < 4; ++r) {
                    float hnew = (1.0f - ALPHA) * mst[j][r] + ALPHA * tanh_fast(acc[r]);
                    mst[j][r] = hnew;
                    int b = m0 + rb + r;
                    int h = n0 + j * 16 + cc;
                    __hip_bfloat16 hb = __float2bfloat16(hnew);
                    Sn[((size_t)l * BB + b) * HH + h] = *(unsigned short*)&hb;
                }
            }
        }
        grid_barrier(bar, s);
    }

    // final fp32 state dump for the readout
#pragma unroll
    for (int j = 0; j < 2; ++j)
#pragma unroll
    for (int r = 0; r < 4; ++r) {
        int b = m0 + rb + r;
        int h = n0 + j * 16 + cc;
        S32[((size_t)l * BB + b) * HH + h] = mst[j][r];
    }
}

// ---------------- readout ----------------
__global__ void out_kernel(const float* __restrict__ S32,
                           const float* __restrict__ w_out,
                           const float* __restrict__ b_out,
                           float* __restrict__ out)
{
    int b = blockIdx.x;
    int tid = threadIdx.x;
    float p = 0.f;
    for (int idx = tid; idx < NL * HH; idx += 256) {
        int l = idx >> 10;
        int h = idx & (HH - 1);
        p += S32[((size_t)l * BB + b) * HH + h] * w_out[idx];
    }
    __shared__ float red[256];
    red[tid] = p;
    __syncthreads();
    for (int off = 128; off > 0; off >>= 1) {
        if (tid < off) red[tid] += red[tid + off];
        __syncthreads();
    }
    if (tid == 0) out[b] = red[0] + b_out[0];
}

extern "C" void kernel_launch(void* const* d_in, const int* in_sizes, int n_in,
                              void* d_out, int out_size, void* d_ws, size_t ws_size,
                              hipStream_t stream)
{
    const float* x         = (const float*)d_in[0];
    const float* W_in0     = (const float*)d_in[1];
    const float* W_in_rest = (const float*)d_in[2];
    const float* W_res     = (const float*)d_in[3];
    const float* w_out     = (const float*)d_in[4];
    const float* b_out     = (const float*)d_in[5];

    char* ws = (char*)d_ws;
    __hip_bfloat16*       Wbh  = (__hip_bfloat16*)(ws + WB_OFF);
    const unsigned short* Wbp  = (const unsigned short*)(ws + WB_OFF);
    unsigned short*       S16p = (unsigned short*)(ws + S16_OFF);
    float*                S32p = (float*)(ws + S32_OFF);
    unsigned int*         barp = (unsigned int*)(ws + BAR_OFF);

    convert_kernel<<<4096, 256, 0, stream>>>(W_in0, W_in_rest, W_res, Wbh);
    // zero S16 (both parity planes) + S32 + barrier block (contiguous)
    hipMemsetAsync(ws + S16_OFF, 0, 6291712, stream);

    void* args[] = { (void*)&x, (void*)&Wbp, (void*)&S16p, (void*)&S32p, (void*)&barp };
    hipLaunchCooperativeKernel((const void*)esn_main, dim3(NWG), dim3(512),
                               args, 0, stream);

    out_kernel<<<BB, 256, 0, stream>>>(S32p, w_out, b_out, (float*)d_out);
}